// Round 1
// baseline (560.272 us; speedup 1.0000x reference)
//
#include <hip/hip_runtime.h>

#define IN_C   16
#define OUT_C  16
#define COEF_M 11
#define PLANE  16384   // 128*128
#define WSIZE  3328    // IN_C*OUT_C*COEF_M + 2*IN_C*OUT_C
#define I0     2816    // IN_C*OUT_C*COEF_M
#define I1     3072    // I0 + IN_C*OUT_C

// block = 256 threads = 64 pixels x 4 i-groups (4 input channels each)
// grid  = 32768 / 64 = 512 blocks -> 2 blocks/CU, 8 waves/CU
__global__ __launch_bounds__(256) void kan_kernel(
    const float* __restrict__ x, const float* __restrict__ w,
    float* __restrict__ out)
{
    const int tid = threadIdx.x;
    const int px  = tid & 63;        // pixel within block
    const int g   = tid >> 6;        // i-group 0..3
    const int pixel = blockIdx.x * 64 + px;
    const int b  = pixel >> 14;      // PLANE = 2^14, blocks never straddle b
    const int hw = pixel & (PLANE - 1);

    const float* wb = w + (size_t)b * WSIZE * PLANE + hw;
    const float* xb = x + (size_t)b * IN_C * PLANE + hw;

    float acc[OUT_C];
    #pragma unroll
    for (int o = 0; o < OUT_C; ++o) acc[o] = 0.0f;

    for (int ii = 0; ii < 4; ++ii) {
        const int i = g * 4 + ii;
        const float xi = xb[(size_t)i * PLANE];

        // Cox-de Boor, order K=3, uniform knots t_j = -1.75 + 0.25*j, j = 0..14
        float bp[14];
        #pragma unroll
        for (int j = 0; j < 14; ++j) {
            const float tj  = -1.75f + 0.25f * j;
            const float tj1 = tj + 0.25f;
            bp[j] = (xi >= tj && xi < tj1) ? 1.0f : 0.0f;
        }
        #pragma unroll
        for (int p = 1; p <= 3; ++p) {
            const float inv = 1.0f / (0.25f * (float)p);
            #pragma unroll
            for (int j = 0; j < 14 - p; ++j) {
                const float tj    = -1.75f + 0.25f * j;
                const float left  = (xi - tj) * inv;
                const float right = ((tj + 0.25f * (float)(p + 1)) - xi) * inv;
                bp[j] = left * bp[j] + right * bp[j + 1];
            }
        }

        const float sx = xi / (1.0f + __expf(-xi));   // silu

        const float* ci = wb + (size_t)(i * (OUT_C * COEF_M)) * PLANE;
        const float* ui = wb + (size_t)(I0 + i * OUT_C) * PLANE;
        const float* ri = wb + (size_t)(I1 + i * OUT_C) * PLANE;

        #pragma unroll
        for (int o = 0; o < OUT_C; ++o) {
            const float* c = ci + (size_t)(o * COEF_M) * PLANE;
            float sp = 0.0f;
            #pragma unroll
            for (int m = 0; m < COEF_M; ++m)
                sp += c[(size_t)m * PLANE] * bp[m];
            acc[o] += ui[(size_t)o * PLANE] * sp + ri[(size_t)o * PLANE] * sx;
        }
    }

    // reduce partial acc across the 4 i-groups via LDS (stride 17 -> <=2-way bank aliasing)
    __shared__ float red[4 * 64 * 17];
    #pragma unroll
    for (int o = 0; o < OUT_C; ++o)
        red[(g * 64 + px) * 17 + o] = acc[o];
    __syncthreads();

    const int og = g;   // 0..3, one o-quad per wave -> coalesced stores
    #pragma unroll
    for (int k = 0; k < 4; ++k) {
        const int o = og * 4 + k;
        const float s = red[(0 * 64 + px) * 17 + o]
                      + red[(1 * 64 + px) * 17 + o]
                      + red[(2 * 64 + px) * 17 + o]
                      + red[(3 * 64 + px) * 17 + o];
        out[(size_t)b * (OUT_C * PLANE) + (size_t)o * PLANE + hw] = s;
    }
}

extern "C" void kernel_launch(void* const* d_in, const int* in_sizes, int n_in,
                              void* d_out, int out_size, void* d_ws, size_t ws_size,
                              hipStream_t stream) {
    const float* x = (const float*)d_in[0];   // (2,16,128,128) fp32
    const float* w = (const float*)d_in[1];   // (2,3328,128,128) fp32
    float* out = (float*)d_out;               // (2,16,128,128) fp32

    kan_kernel<<<dim3(512), dim3(256), 0, stream>>>(x, w, out);
}